// Round 1
// baseline (656.771 us; speedup 1.0000x reference)
//
#include <hip/hip_runtime.h>
#include <math.h>

#define N_PIX 65536
#define EPSF 1e-6f
#define INV_FALLOFF 50.0f   // 1/0.02
#define CHUNKS 32
#define PIX_PER_CHUNK 2048  // 65536/32
#define TILE_P 64
#define N_JOBS 48           // 2 imgs * 8 batch * 3 channels

__device__ __forceinline__ float rcp_fast(float x) { return __builtin_amdgcn_rcpf(x); }

// ---------------------------------------------------------------------------
// Kernel 1: per (img, batch, channel, k-chunk) partial 64x64 histogram.
// 256 threads = 4 waves. Each wave processes 16 pixels/tile; each lane owns an
// 8x8 accumulator tile (64 VGPRs) of the 64x64 output.
// ---------------------------------------------------------------------------
__global__ __launch_bounds__(256) void hist_partial_kernel(
    const float* __restrict__ x, const float* __restrict__ y,
    float* __restrict__ partial)
{
    const int blk = blockIdx.x;            // 0..1535
    const int chunk = blk & (CHUNKS - 1);
    const int job = blk / CHUNKS;          // 0..47
    const int c = job % 3;
    const int ib = job / 3;                // img*8 + b
    const int img = ib >> 3;
    const int b = ib & 7;
    const float* __restrict__ src = (img == 0 ? x : y) + (size_t)b * 3 * N_PIX;

    __shared__ float abw[TILE_P * 128];    // [pixel][0:64]=w*rbf(u), [64:128]=rbf(v)  (32 KB)
    __shared__ float uvw[TILE_P * 3];

    const int tid = threadIdx.x;
    const int lane = tid & 63;
    const int wv = tid >> 6;               // wave 0..3
    const int li = lane >> 3;              // u-block 0..7
    const int lj = lane & 7;               // v-block 0..7

    float acc[8][8];
#pragma unroll
    for (int i = 0; i < 8; ++i)
#pragma unroll
        for (int j = 0; j < 8; ++j) acc[i][j] = 0.0f;

    const int base = chunk * PIX_PER_CHUNK;
    for (int tile = 0; tile < PIX_PER_CHUNK / TILE_P; ++tile) {
        const int pix0 = base + tile * TILE_P;

        // Phase 1a: 64 threads compute (u, v, w) for the tile's 64 pixels.
        if (tid < TILE_P) {
            const int n = pix0 + tid;
            const float r  = src[n] + EPSF;
            const float g  = src[N_PIX + n] + EPSF;
            const float bl = src[2 * N_PIX + n] + EPSF;
            const float w  = sqrtf(fmaf(r, r, fmaf(g, g, bl * bl)));
            const float lr = logf(r), lg = logf(g), lb2 = logf(bl);
            // channel c: u = l_c - l_a, v = l_c - l_b;  c0:(a,b)=(g,b) c1:(r,b) c2:(r,g)
            const float l0 = (c == 0) ? lr : ((c == 1) ? lg : lb2);
            const float lu = (c == 0) ? lg : lr;
            const float lv = (c == 2) ? lg : lb2;
            uvw[tid * 3 + 0] = l0 - lu;
            uvw[tid * 3 + 1] = l0 - lv;
            uvw[tid * 3 + 2] = w;
        }
        __syncthreads();

        // Phase 1b: cooperatively compute all 64*128 RBF values (one rcp each).
#pragma unroll
        for (int i = 0; i < 32; ++i) {
            const int e = i * 256 + tid;   // 0..8191
            const int p = e >> 7;          // pixel 0..63
            const int k = e & 127;         // 0..63 -> u-centers, 64..127 -> v-centers
            const float d = (k < 64) ? uvw[p * 3 + 0] : uvw[p * 3 + 1];
            const float cc = -3.0f + (float)(k & 63) * (6.0f / 63.0f);
            const float wmul = (k < 64) ? uvw[p * 3 + 2] : 1.0f;  // fold w into the u side
            const float t = (d - cc) * INV_FALLOFF;
            const float q = fmaf(t, t, 1.0f);
            abw[p * 128 + k] = wmul * rcp_fast(q);
        }
        __syncthreads();

        // Phase 2: wave wv takes pixels [wv*16, wv*16+16); 8x8 register tile/lane.
        const int p0 = wv * 16;
#pragma unroll 2
        for (int pp = 0; pp < 16; ++pp) {
            const int p = p0 + pp;
            const float4 a0 = *(const float4*)&abw[p * 128 + li * 8];
            const float4 a1 = *(const float4*)&abw[p * 128 + li * 8 + 4];
            const float4 b0 = *(const float4*)&abw[p * 128 + 64 + lj * 8];
            const float4 b1 = *(const float4*)&abw[p * 128 + 64 + lj * 8 + 4];
            const float av[8] = {a0.x, a0.y, a0.z, a0.w, a1.x, a1.y, a1.z, a1.w};
            const float bv[8] = {b0.x, b0.y, b0.z, b0.w, b1.x, b1.y, b1.z, b1.w};
#pragma unroll
            for (int ii = 0; ii < 8; ++ii)
#pragma unroll
                for (int jj = 0; jj < 8; ++jj)
                    acc[ii][jj] = fmaf(av[ii], bv[jj], acc[ii][jj]);
        }
        __syncthreads();   // protect abw/uvw before next tile overwrites
    }

    // Block-reduce the 4 waves' full-64x64 accumulators (reuse abw as hist[4096]).
    float* hist = abw;
    for (int i = tid; i < 4096; i += 256) hist[i] = 0.0f;
    __syncthreads();
#pragma unroll
    for (int ii = 0; ii < 8; ++ii)
#pragma unroll
        for (int jj = 0; jj < 8; ++jj) {
            const int e = (li * 8 + ii) * 64 + (lj * 8 + jj);
            atomicAdd(&hist[e], acc[ii][jj]);   // 4-way contention only
        }
    __syncthreads();

    float* outp = partial + (size_t)blk * 4096;
    for (int i = tid; i < 4096; i += 256) outp[i] = hist[i];
}

// ---------------------------------------------------------------------------
// Kernel 2: sum the 32 chunk-partials of each job -> hist[48][4096]
// ---------------------------------------------------------------------------
__global__ __launch_bounds__(256) void reduce_partials_kernel(
    const float* __restrict__ partial, float* __restrict__ hist)
{
    const int job = blockIdx.x >> 4;                       // 0..47
    const int e = ((blockIdx.x & 15) << 8) | threadIdx.x;  // 0..4095
    const float* p = partial + (size_t)job * CHUNKS * 4096 + e;
    float s = 0.0f;
#pragma unroll
    for (int k = 0; k < CHUNKS; ++k) s += p[(size_t)k * 4096];
    hist[(size_t)job * 4096 + e] = s;
}

// ---------------------------------------------------------------------------
// Kernel 3: per-batch normalization + Hellinger-style distance.
// ---------------------------------------------------------------------------
__device__ __forceinline__ float block_sum(float v, float* red) {
#pragma unroll
    for (int o = 32; o > 0; o >>= 1) v += __shfl_down(v, o, 64);
    const int wv = threadIdx.x >> 6;
    __syncthreads();
    if ((threadIdx.x & 63) == 0) red[wv] = v;
    __syncthreads();
    return red[0] + red[1] + red[2] + red[3];
}

__global__ __launch_bounds__(256) void loss_kernel(
    const float* __restrict__ hist, float* __restrict__ hnorm)
{
    const int b = blockIdx.x;  // 0..7
    __shared__ float red[4];
    const int tid = threadIdx.x;
    const float* xh = hist + (size_t)(b * 3) * 4096;        // jobs (0*8+b)*3 + c
    const float* yh = hist + (size_t)((8 + b) * 3) * 4096;  // jobs (1*8+b)*3 + c

    float sx = 0.0f, sy = 0.0f;
    for (int i = tid; i < 3 * 4096; i += 256) { sx += xh[i]; sy += yh[i]; }
    const float tx = block_sum(sx, red);
    const float ty = block_sum(sy, red);
    const float invx = 1.0f / tx, invy = 1.0f / ty;

    float h = 0.0f;
    for (int i = tid; i < 3 * 4096; i += 256) {
        const float d = sqrtf(yh[i] * invy) - sqrtf(xh[i] * invx);
        h = fmaf(d, d, h);
    }
    h = block_sum(h, red);
    if (tid == 0) hnorm[b] = sqrtf(0.5f * h);
}

// ---------------------------------------------------------------------------
// Kernel 4: mean over batch -> out[0]
// ---------------------------------------------------------------------------
__global__ void final_kernel(const float* __restrict__ hnorm, float* __restrict__ out)
{
    if (threadIdx.x == 0) {
        float s = 0.0f;
#pragma unroll
        for (int i = 0; i < 8; ++i) s += hnorm[i];
        out[0] = s * 0.125f;
    }
}

extern "C" void kernel_launch(void* const* d_in, const int* in_sizes, int n_in,
                              void* d_out, int out_size, void* d_ws, size_t ws_size,
                              hipStream_t stream)
{
    const float* x = (const float*)d_in[0];
    const float* y = (const float*)d_in[1];
    float* ws = (float*)d_ws;
    float* partial = ws;                                      // 1536*4096 floats (25.2 MB)
    float* hist = ws + (size_t)N_JOBS * CHUNKS * 4096;        // 48*4096
    float* hnorm = hist + (size_t)N_JOBS * 4096;              // 8
    float* outf = (float*)d_out;

    hipLaunchKernelGGL(hist_partial_kernel, dim3(N_JOBS * CHUNKS), dim3(256), 0, stream,
                       x, y, partial);
    hipLaunchKernelGGL(reduce_partials_kernel, dim3(N_JOBS * 16), dim3(256), 0, stream,
                       partial, hist);
    hipLaunchKernelGGL(loss_kernel, dim3(8), dim3(256), 0, stream, hist, hnorm);
    hipLaunchKernelGGL(final_kernel, dim3(1), dim3(64), 0, stream, hnorm, outf);
}

// Round 2
// 463.962 us; speedup vs baseline: 1.4156x; 1.4156x over previous
//
#include <hip/hip_runtime.h>
#include <math.h>

#define N_PIX 65536
#define EPSF 1e-6f
#define CHUNKS 16
#define PX_PER_CHUNK 4096   // 65536 / 16
#define PX_PER_WAVE 1024    // 4 waves per block
#define N_JOBS 48           // 2 imgs * 8 batch * 3 channels

__device__ __forceinline__ float rcp_fast(float x) { return __builtin_amdgcn_rcpf(x); }
__device__ __forceinline__ float rdlane(float v, int l) {
    return __builtin_bit_cast(float, __builtin_amdgcn_readlane(__builtin_bit_cast(int, v), l));
}

// ---------------------------------------------------------------------------
// Kernel 1: per (job, chunk) partial 64x64 histogram. 4 waves/block, each wave
// fully independent (private 8KB LDS region, own 1024-pixel strip) -> no
// __syncthreads in the hot loop. Each lane holds an 8x8 accumulator tile.
// ---------------------------------------------------------------------------
__global__ __launch_bounds__(256) void hist_partial_kernel(
    const float* __restrict__ x, const float* __restrict__ y,
    float* __restrict__ partial)
{
    const int blk = blockIdx.x;            // 0..767
    const int chunk = blk & (CHUNKS - 1);
    const int job = blk / CHUNKS;          // 0..47
    const int c = job % 3;
    const int ib = job / 3;                // img*8 + b
    const int img = ib >> 3;
    const int b = ib & 7;
    const float* __restrict__ src = (img == 0 ? x : y) + (size_t)b * 3 * N_PIX;

    __shared__ float lds[8192];            // 32 KB: wave w owns lds[w*2048 .. +2048)
    const int tid = threadIdx.x;
    const int lane = tid & 63;
    const int wv = tid >> 6;
    float* __restrict__ myab = lds + wv * 2048;   // [16 px][128] : 0:64 w*rbf(u), 64:128 rbf(v)

    const int li = lane >> 3;              // u-block 0..7
    const int lj = lane & 7;               // v-block 0..7
    const float c50 = (-3.0f + (float)lane * (6.0f / 63.0f)) * 50.0f;  // center*INV_FALLOFF

    float acc[8][8];
#pragma unroll
    for (int i = 0; i < 8; ++i)
#pragma unroll
        for (int j = 0; j < 8; ++j) acc[i][j] = 0.0f;

    const int px0 = chunk * PX_PER_CHUNK + wv * PX_PER_WAVE;

    for (int st = 0; st < PX_PER_WAVE / 64; ++st) {   // 16 super-tiles of 64 px
        // Phase A: one pixel per lane — all 64 lanes busy.
        const int n = px0 + st * 64 + lane;
        const float r  = src[n] + EPSF;
        const float g  = src[N_PIX + n] + EPSF;
        const float bl = src[2 * N_PIX + n] + EPSF;
        const float wgt = sqrtf(fmaf(r, r, fmaf(g, g, bl * bl)));
        const float lr = __logf(r), lg = __logf(g), lb2 = __logf(bl);
        // channel c: u = l_c - l_a, v = l_c - l_b;  c0:(a,b)=(g,b) c1:(r,b) c2:(r,g)
        const float l0 = (c == 0) ? lr : ((c == 1) ? lg : lb2);
        const float lu = (c == 0) ? lg : lr;
        const float lv = (c == 2) ? lg : lb2;
        const float u50 = (l0 - lu) * 50.0f;
        const float v50 = (l0 - lv) * 50.0f;

        for (int sub = 0; sub < 4; ++sub) {          // 16-px sub-tiles
            // Phase B: RBF generation. Pixel sp lives in lane sub*16+pp;
            // broadcast via readlane, each lane evaluates its own 2 centers.
#pragma unroll
            for (int pp = 0; pp < 16; ++pp) {
                const int sl = sub * 16 + pp;
                const float su = rdlane(u50, sl);
                const float sv = rdlane(v50, sl);
                const float sw = rdlane(wgt, sl);
                const float tu = su - c50;
                const float au = sw * rcp_fast(fmaf(tu, tu, 1.0f));
                const float tv = sv - c50;
                const float bv = rcp_fast(fmaf(tv, tv, 1.0f));
                myab[pp * 128 + lane] = au;          // same-wave DS: in-order, no barrier
                myab[pp * 128 + 64 + lane] = bv;
            }

            // Phase C: 8x8 register-tile FMA over the 16 pixels.
            const float* pa = myab + li * 8;
            const float* pb = myab + 64 + lj * 8;
#pragma unroll 4
            for (int pp = 0; pp < 16; ++pp) {
                const float4 a0 = *(const float4*)(pa + pp * 128);
                const float4 a1 = *(const float4*)(pa + pp * 128 + 4);
                const float4 b0 = *(const float4*)(pb + pp * 128);
                const float4 b1 = *(const float4*)(pb + pp * 128 + 4);
                const float avv[8] = {a0.x, a0.y, a0.z, a0.w, a1.x, a1.y, a1.z, a1.w};
                const float bvv[8] = {b0.x, b0.y, b0.z, b0.w, b1.x, b1.y, b1.z, b1.w};
#pragma unroll
                for (int ii = 0; ii < 8; ++ii)
#pragma unroll
                    for (int jj = 0; jj < 8; ++jj)
                        acc[ii][jj] = fmaf(avv[ii], bvv[jj], acc[ii][jj]);
            }
        }
    }

    // Block-reduce the 4 waves (only barriers in the kernel).
    __syncthreads();
    for (int i = tid; i < 4096; i += 256) lds[i] = 0.0f;
    __syncthreads();
#pragma unroll
    for (int ii = 0; ii < 8; ++ii)
#pragma unroll
        for (int jj = 0; jj < 8; ++jj)
            atomicAdd(&lds[(li * 8 + ii) * 64 + (lj * 8 + jj)], acc[ii][jj]);
    __syncthreads();

    float* outp = partial + (size_t)blk * 4096;
    for (int i = tid; i < 4096; i += 256) outp[i] = lds[i];
}

// ---------------------------------------------------------------------------
// Kernel 2: sum the 16 chunk-partials of each job -> hist[48][4096]
// ---------------------------------------------------------------------------
__global__ __launch_bounds__(256) void reduce_partials_kernel(
    const float* __restrict__ partial, float* __restrict__ hist)
{
    const int job = blockIdx.x >> 4;                       // 0..47
    const int e = ((blockIdx.x & 15) << 8) | threadIdx.x;  // 0..4095
    const float* p = partial + (size_t)job * CHUNKS * 4096 + e;
    float s = 0.0f;
#pragma unroll
    for (int k = 0; k < CHUNKS; ++k) s += p[(size_t)k * 4096];
    hist[(size_t)job * 4096 + e] = s;
}

// ---------------------------------------------------------------------------
// Kernel 3: per-batch normalization + Hellinger-style distance.
// ---------------------------------------------------------------------------
__device__ __forceinline__ float block_sum(float v, float* red) {
#pragma unroll
    for (int o = 32; o > 0; o >>= 1) v += __shfl_down(v, o, 64);
    const int wv = threadIdx.x >> 6;
    __syncthreads();
    if ((threadIdx.x & 63) == 0) red[wv] = v;
    __syncthreads();
    return red[0] + red[1] + red[2] + red[3];
}

__global__ __launch_bounds__(256) void loss_kernel(
    const float* __restrict__ hist, float* __restrict__ hnorm)
{
    const int b = blockIdx.x;  // 0..7
    __shared__ float red[4];
    const int tid = threadIdx.x;
    const float* xh = hist + (size_t)(b * 3) * 4096;        // img 0
    const float* yh = hist + (size_t)((8 + b) * 3) * 4096;  // img 1

    float sx = 0.0f, sy = 0.0f;
    for (int i = tid; i < 3 * 4096; i += 256) { sx += xh[i]; sy += yh[i]; }
    const float tx = block_sum(sx, red);
    __syncthreads();
    const float ty = block_sum(sy, red);
    const float invx = 1.0f / tx, invy = 1.0f / ty;

    float h = 0.0f;
    for (int i = tid; i < 3 * 4096; i += 256) {
        const float d = sqrtf(yh[i] * invy) - sqrtf(xh[i] * invx);
        h = fmaf(d, d, h);
    }
    __syncthreads();
    h = block_sum(h, red);
    if (tid == 0) hnorm[b] = sqrtf(0.5f * h);
}

// ---------------------------------------------------------------------------
// Kernel 4: mean over batch -> out[0]
// ---------------------------------------------------------------------------
__global__ void final_kernel(const float* __restrict__ hnorm, float* __restrict__ out)
{
    if (threadIdx.x == 0) {
        float s = 0.0f;
#pragma unroll
        for (int i = 0; i < 8; ++i) s += hnorm[i];
        out[0] = s * 0.125f;
    }
}

extern "C" void kernel_launch(void* const* d_in, const int* in_sizes, int n_in,
                              void* d_out, int out_size, void* d_ws, size_t ws_size,
                              hipStream_t stream)
{
    const float* x = (const float*)d_in[0];
    const float* y = (const float*)d_in[1];
    float* ws = (float*)d_ws;
    float* partial = ws;                                      // 768*4096 floats (12.6 MB)
    float* hist = ws + (size_t)N_JOBS * CHUNKS * 4096;        // 48*4096
    float* hnorm = hist + (size_t)N_JOBS * 4096;              // 8
    float* outf = (float*)d_out;

    hipLaunchKernelGGL(hist_partial_kernel, dim3(N_JOBS * CHUNKS), dim3(256), 0, stream,
                       x, y, partial);
    hipLaunchKernelGGL(reduce_partials_kernel, dim3(N_JOBS * 16), dim3(256), 0, stream,
                       partial, hist);
    hipLaunchKernelGGL(loss_kernel, dim3(8), dim3(256), 0, stream, hist, hnorm);
    hipLaunchKernelGGL(final_kernel, dim3(1), dim3(64), 0, stream, hnorm, outf);
}

// Round 3
// 271.393 us; speedup vs baseline: 2.4200x; 1.7096x over previous
//
#include <hip/hip_runtime.h>
#include <math.h>

#define N_PIX 65536
#define EPSF 1e-6f
#define CHUNKS 16
#define PX_PER_CHUNK 4096   // 65536 / 16
#define PX_PER_WAVE 1024    // 4 waves per block
#define N_JOBS 48           // 2 imgs * 8 batch * 3 channels

using short8 = __attribute__((ext_vector_type(8))) short;
using f32x4  = __attribute__((ext_vector_type(4))) float;

__device__ __forceinline__ float rcp_fast(float x) { return __builtin_amdgcn_rcpf(x); }
__device__ __forceinline__ float rdlane(float v, int l) {
    return __builtin_bit_cast(float, __builtin_amdgcn_readlane(__builtin_bit_cast(int, v), l));
}
// pack two fp32 -> bf16x2 (round-to-nearest-even); low = a, high = b
__device__ __forceinline__ uint32_t pk_bf16(float a, float b) {
    uint32_t ua = __builtin_bit_cast(uint32_t, a);
    uint32_t ub = __builtin_bit_cast(uint32_t, b);
    ua += 0x7FFFu + ((ua >> 16) & 1u);
    ub += 0x7FFFu + ((ub >> 16) & 1u);
    return (ua >> 16) | (ub & 0xFFFF0000u);
}

// ---------------------------------------------------------------------------
// Kernel 1: per (job, chunk) partial 64x64 histogram via bf16 MFMA.
// hist = U^T * V, U[k][m] = w_k * rbf(u_k, c_m), V[k][n] = rbf(v_k, c_n).
// 4 independent waves/block (private 8KB LDS region, own 1024-px strip), no
// __syncthreads in the hot loop. Each wave computes the full 64x64 with a
// 4x4 grid of 16x16x32 MFMA tiles.
// LDS layout per wave: U_lds[64 bins][32 k] bf16, XOR-swizzled at 16B
// granularity (group g of row r stored at g^(r&3)) so both the per-lane row
// writes and the fragment reads spread over all banks. Same for V_lds.
// ---------------------------------------------------------------------------
__global__ __launch_bounds__(256) void hist_partial_kernel(
    const float* __restrict__ x, const float* __restrict__ y,
    float* __restrict__ partial)
{
    const int blk = blockIdx.x;            // 0..767
    const int chunk = blk & (CHUNKS - 1);
    const int job = blk / CHUNKS;          // 0..47
    const int c = job % 3;
    const int ib = job / 3;                // img*8 + b
    const int img = ib >> 3;
    const int b = ib & 7;
    const float* __restrict__ src = (img == 0 ? x : y) + (size_t)b * 3 * N_PIX;

    __shared__ __align__(16) unsigned short stage[16384];  // 32 KB
    const int tid = threadIdx.x;
    const int lane = tid & 63;
    const int wv = tid >> 6;
    unsigned short* __restrict__ myU = stage + wv * 4096;  // [64][32] bf16
    unsigned short* __restrict__ myV = myU + 2048;         // [64][32] bf16

    const int quad = lane >> 4;
    const int l15 = lane & 15;
    const float c50 = (-3.0f + (float)lane * (6.0f / 63.0f)) * 50.0f;  // center/FALL_OFF

    f32x4 acc[16];                         // acc[mt*4+nt]
#pragma unroll
    for (int i = 0; i < 16; ++i) acc[i] = (f32x4){0.f, 0.f, 0.f, 0.f};

    const int px0 = chunk * PX_PER_CHUNK + wv * PX_PER_WAVE;

    for (int st = 0; st < PX_PER_WAVE / 64; ++st) {   // 16 super-tiles of 64 px
        // ---- Phase A: one pixel per lane ----
        const int n = px0 + st * 64 + lane;
        const float r  = src[n] + EPSF;
        const float g  = src[N_PIX + n] + EPSF;
        const float bl = src[2 * N_PIX + n] + EPSF;
        const float wgt = sqrtf(fmaf(r, r, fmaf(g, g, bl * bl)));
        const float lr = __logf(r), lg = __logf(g), lb2 = __logf(bl);
        // channel c: u = l_c - l_a, v = l_c - l_b;  c0:(a,b)=(g,b) c1:(r,b) c2:(r,g)
        const float l0 = (c == 0) ? lr : ((c == 1) ? lg : lb2);
        const float lu = (c == 0) ? lg : lr;
        const float lv = (c == 2) ? lg : lb2;
        const float u50 = (l0 - lu) * 50.0f;
        const float v50 = (l0 - lv) * 50.0f;

#pragma unroll
        for (int h = 0; h < 2; ++h) {      // two K=32 halves
            // ---- Phase B: generate + pack 32 pixels' RBF rows ----
#pragma unroll
            for (int g8 = 0; g8 < 4; ++g8) {
                uint32_t up[4], vp[4];
#pragma unroll
                for (int q = 0; q < 4; ++q) {
                    const int t0 = h * 32 + g8 * 8 + q * 2;   // compile-time lane idx
                    const float su0 = rdlane(u50, t0),     sv0 = rdlane(v50, t0),     sw0 = rdlane(wgt, t0);
                    const float su1 = rdlane(u50, t0 + 1), sv1 = rdlane(v50, t0 + 1), sw1 = rdlane(wgt, t0 + 1);
                    const float tu0 = su0 - c50, tv0 = sv0 - c50;
                    const float tu1 = su1 - c50, tv1 = sv1 - c50;
                    const float ua0 = sw0 * rcp_fast(fmaf(tu0, tu0, 1.0f));
                    const float ua1 = sw1 * rcp_fast(fmaf(tu1, tu1, 1.0f));
                    const float va0 = rcp_fast(fmaf(tv0, tv0, 1.0f));
                    const float va1 = rcp_fast(fmaf(tv1, tv1, 1.0f));
                    up[q] = pk_bf16(ua0, ua1);
                    vp[q] = pk_bf16(va0, va1);
                }
                const int off = lane * 32 + ((g8 ^ (lane & 3)) << 3);  // ushort units
                *(uint4*)(myU + off) = make_uint4(up[0], up[1], up[2], up[3]);
                *(uint4*)(myV + off) = make_uint4(vp[0], vp[1], vp[2], vp[3]);
            }

            // ---- Phase C: fragment loads + 16 MFMA ----
            short8 af[4], bf[4];
#pragma unroll
            for (int mt = 0; mt < 4; ++mt) {
                const int row = mt * 16 + l15;
                const int off = row * 32 + ((quad ^ (row & 3)) << 3);
                af[mt] = __builtin_bit_cast(short8, *(const uint4*)(myU + off));
                bf[mt] = __builtin_bit_cast(short8, *(const uint4*)(myV + off));
            }
#pragma unroll
            for (int mt = 0; mt < 4; ++mt)
#pragma unroll
                for (int nt = 0; nt < 4; ++nt)
                    acc[mt * 4 + nt] = __builtin_amdgcn_mfma_f32_16x16x32_bf16(
                        af[mt], bf[nt], acc[mt * 4 + nt], 0, 0, 0);
        }
    }

    // ---- Block-reduce the 4 waves (only barriers in the kernel) ----
    float* hfl = (float*)stage;            // 4096 f32 = 16 KB
    __syncthreads();
    for (int i = tid; i < 4096; i += 256) hfl[i] = 0.0f;
    __syncthreads();
#pragma unroll
    for (int mt = 0; mt < 4; ++mt)
#pragma unroll
        for (int nt = 0; nt < 4; ++nt)
#pragma unroll
            for (int i = 0; i < 4; ++i) {
                const int m = mt * 16 + quad * 4 + i;   // C/D: row = quad*4+reg
                const int nn = nt * 16 + l15;           //      col = lane&15
                atomicAdd(&hfl[m * 64 + nn], acc[mt * 4 + nt][i]);
            }
    __syncthreads();

    float* outp = partial + (size_t)blk * 4096;
    for (int i = tid; i < 4096; i += 256) outp[i] = hfl[i];
}

// ---------------------------------------------------------------------------
// Kernel 2: sum the 16 chunk-partials of each job -> hist[48][4096]
// ---------------------------------------------------------------------------
__global__ __launch_bounds__(256) void reduce_partials_kernel(
    const float* __restrict__ partial, float* __restrict__ hist)
{
    const int job = blockIdx.x >> 4;                       // 0..47
    const int e = ((blockIdx.x & 15) << 8) | threadIdx.x;  // 0..4095
    const float* p = partial + (size_t)job * CHUNKS * 4096 + e;
    float s = 0.0f;
#pragma unroll
    for (int k = 0; k < CHUNKS; ++k) s += p[(size_t)k * 4096];
    hist[(size_t)job * 4096 + e] = s;
}

// ---------------------------------------------------------------------------
// Kernel 3: per-batch normalization + Hellinger-style distance.
// ---------------------------------------------------------------------------
__device__ __forceinline__ float block_sum(float v, float* red) {
#pragma unroll
    for (int o = 32; o > 0; o >>= 1) v += __shfl_down(v, o, 64);
    const int wv = threadIdx.x >> 6;
    __syncthreads();
    if ((threadIdx.x & 63) == 0) red[wv] = v;
    __syncthreads();
    return red[0] + red[1] + red[2] + red[3];
}

__global__ __launch_bounds__(256) void loss_kernel(
    const float* __restrict__ hist, float* __restrict__ hnorm)
{
    const int b = blockIdx.x;  // 0..7
    __shared__ float red[4];
    const int tid = threadIdx.x;
    const float* xh = hist + (size_t)(b * 3) * 4096;        // img 0
    const float* yh = hist + (size_t)((8 + b) * 3) * 4096;  // img 1

    float sx = 0.0f, sy = 0.0f;
    for (int i = tid; i < 3 * 4096; i += 256) { sx += xh[i]; sy += yh[i]; }
    const float tx = block_sum(sx, red);
    __syncthreads();
    const float ty = block_sum(sy, red);
    const float invx = 1.0f / tx, invy = 1.0f / ty;

    float h = 0.0f;
    for (int i = tid; i < 3 * 4096; i += 256) {
        const float d = sqrtf(yh[i] * invy) - sqrtf(xh[i] * invx);
        h = fmaf(d, d, h);
    }
    __syncthreads();
    h = block_sum(h, red);
    if (tid == 0) hnorm[b] = sqrtf(0.5f * h);
}

// ---------------------------------------------------------------------------
// Kernel 4: mean over batch -> out[0]
// ---------------------------------------------------------------------------
__global__ void final_kernel(const float* __restrict__ hnorm, float* __restrict__ out)
{
    if (threadIdx.x == 0) {
        float s = 0.0f;
#pragma unroll
        for (int i = 0; i < 8; ++i) s += hnorm[i];
        out[0] = s * 0.125f;
    }
}

extern "C" void kernel_launch(void* const* d_in, const int* in_sizes, int n_in,
                              void* d_out, int out_size, void* d_ws, size_t ws_size,
                              hipStream_t stream)
{
    const float* x = (const float*)d_in[0];
    const float* y = (const float*)d_in[1];
    float* ws = (float*)d_ws;
    float* partial = ws;                                      // 768*4096 floats (12.6 MB)
    float* hist = ws + (size_t)N_JOBS * CHUNKS * 4096;        // 48*4096
    float* hnorm = hist + (size_t)N_JOBS * 4096;              // 8
    float* outf = (float*)d_out;

    hipLaunchKernelGGL(hist_partial_kernel, dim3(N_JOBS * CHUNKS), dim3(256), 0, stream,
                       x, y, partial);
    hipLaunchKernelGGL(reduce_partials_kernel, dim3(N_JOBS * 16), dim3(256), 0, stream,
                       partial, hist);
    hipLaunchKernelGGL(loss_kernel, dim3(8), dim3(256), 0, stream, hist, hnorm);
    hipLaunchKernelGGL(final_kernel, dim3(1), dim3(64), 0, stream, hnorm, outf);
}

// Round 4
// 210.596 us; speedup vs baseline: 3.1186x; 1.2887x over previous
//
#include <hip/hip_runtime.h>
#include <math.h>

#define N_PIX 65536
#define EPSF 1e-6f
#define CHUNKS 16
#define PX_PER_CHUNK 4096   // 65536 / 16
#define PX_PER_WAVE 1024    // 4 waves per block, 16 super-tiles of 64 px
#define N_JOBS 48           // 2 imgs * 8 batch * 3 channels

typedef __attribute__((ext_vector_type(2))) float f2;
using short8 = __attribute__((ext_vector_type(8))) short;
using f32x4  = __attribute__((ext_vector_type(4))) float;

__device__ __forceinline__ float rcp_fast(float x) { return __builtin_amdgcn_rcpf(x); }

// round-half-up bf16 pack: {lo=a, hi=b}. All inputs are positive finite, so
// +0x8000 then truncate is correct round-half-up (bias <= 1/2 ulp vs RNE).
__device__ __forceinline__ uint32_t pk_bf16_rhu(float a, float b) {
    const uint32_t ua = __builtin_bit_cast(uint32_t, a) + 0x8000u;
    const uint32_t ub = __builtin_bit_cast(uint32_t, b) + 0x8000u;
    // result bytes: {ua.b2, ua.b3, ub.b2, ub.b3}  (perm: idx 0-3 = src1, 4-7 = src0)
    return __builtin_amdgcn_perm(ub, ua, 0x07060302u);
}

// ---------------------------------------------------------------------------
// Kernel 1: per (job, chunk) 64x64 histogram contribution via bf16 MFMA with
// fragment-direct operand generation (no U/V staging matrices in LDS).
// Per wave (private 1KB LDS): phase A computes (u*50, v*50, w) per pixel
// (lane = pixel) and stores float4; phase B: each lane evaluates exactly the
// RBF values its MFMA fragments need (A[m=l15][k=quad*8+j], 4 m-tiles), using
// broadcast ds_read_b128 + rcp-of-product; packs pairs with v_perm; 16 MFMA
// per K=32 half. Epilogue: 4-wave LDS reduce, then global atomicAdd into hist.
// ---------------------------------------------------------------------------
__global__ __launch_bounds__(256, 3) void hist_kernel(
    const float* __restrict__ x, const float* __restrict__ y,
    float* __restrict__ hist)
{
    const int blk = blockIdx.x;            // 0..767
    const int chunk = blk & (CHUNKS - 1);
    const int job = blk / CHUNKS;          // 0..47
    const int c = job % 3;
    const int ib = job / 3;                // img*8 + b
    const int img = ib >> 3;
    const int b = ib & 7;
    const float* __restrict__ src = (img == 0 ? x : y) + (size_t)b * 3 * N_PIX;

    __shared__ __align__(16) float lds[4096];   // 16 KB (phase buffers / reduce)
    const int tid = threadIdx.x;
    const int lane = tid & 63;
    const int wv = tid >> 6;
    float* __restrict__ wbuf = lds + wv * 256;  // 64 px * float4

    const int quad = lane >> 4;
    const int l15 = lane & 15;
    // negated scaled centers for this lane's 4 m-rows: -(c_m * 50), m = mt*16+l15
    f2 ncb01, ncb23;
    {
        const float c0 = (-3.0f + (float)(l15)      * (6.0f / 63.0f)) * 50.0f;
        const float c1 = (-3.0f + (float)(16 + l15) * (6.0f / 63.0f)) * 50.0f;
        const float c2 = (-3.0f + (float)(32 + l15) * (6.0f / 63.0f)) * 50.0f;
        const float c3 = (-3.0f + (float)(48 + l15) * (6.0f / 63.0f)) * 50.0f;
        ncb01 = (f2){-c0, -c1};
        ncb23 = (f2){-c2, -c3};
    }
    const f2 one2 = {1.0f, 1.0f};

    f32x4 acc[16];                         // acc[mt*4+nt]
#pragma unroll
    for (int i = 0; i < 16; ++i) acc[i] = (f32x4){0.f, 0.f, 0.f, 0.f};

    const int px0 = chunk * PX_PER_CHUNK + wv * PX_PER_WAVE;

    for (int st = 0; st < PX_PER_WAVE / 64; ++st) {   // 16 super-tiles of 64 px
        // ---- Phase A: one pixel per lane ----
        const int n = px0 + st * 64 + lane;
        const float r  = src[n] + EPSF;
        const float g  = src[N_PIX + n] + EPSF;
        const float bl = src[2 * N_PIX + n] + EPSF;
        const float wgt = sqrtf(fmaf(r, r, fmaf(g, g, bl * bl)));
        const float lr = __logf(r), lg = __logf(g), lb2 = __logf(bl);
        // channel c: u = l_c - l_a, v = l_c - l_b;  c0:(a,b)=(g,b) c1:(r,b) c2:(r,g)
        const float l0 = (c == 0) ? lr : ((c == 1) ? lg : lb2);
        const float lu = (c == 0) ? lg : lr;
        const float lv = (c == 2) ? lg : lb2;
        const float4 uvw = make_float4((l0 - lu) * 50.0f, (l0 - lv) * 50.0f, wgt, 0.0f);
        *(float4*)(wbuf + lane * 4) = uvw;         // same-wave DS: in-order, no barrier

#pragma unroll
        for (int h = 0; h < 2; ++h) {              // two K=32 halves
            const float4* __restrict__ pbase = (const float4*)(wbuf + (h * 32 + quad * 8) * 4);
            int aU[4][4], aV[4][4];                // fragment words [mt][jp]

#pragma unroll
            for (int jp = 0; jp < 4; ++jp) {       // j = 2jp (even), 2jp+1 (odd)
                const float4 pe = pbase[2 * jp];
                const float4 po = pbase[2 * jp + 1];

                float aue[4], auo[4], bve[4], bvo[4];
#pragma unroll
                for (int eo = 0; eo < 2; ++eo) {
                    const float ru = eo ? po.x : pe.x;
                    const float rv = eo ? po.y : pe.y;
                    const float rw = eo ? po.z : pe.z;
                    float* au = eo ? auo : aue;
                    float* bv = eo ? bvo : bve;

                    const f2 ruu = {ru, ru};
                    const f2 tu01 = ruu + ncb01;
                    const f2 tu23 = ruu + ncb23;
                    const f2 qu01 = __builtin_elementwise_fma(tu01, tu01, one2);
                    const f2 qu23 = __builtin_elementwise_fma(tu23, tu23, one2);
                    // rcp of product: 1 rcp serves 2 denominators (err ~3 ulp fp32)
                    const float Ru0 = rcp_fast(qu01.x * qu01.y) * rw;
                    const float Ru1 = rcp_fast(qu23.x * qu23.y) * rw;
                    au[0] = Ru0 * qu01.y; au[1] = Ru0 * qu01.x;
                    au[2] = Ru1 * qu23.y; au[3] = Ru1 * qu23.x;

                    const f2 rvv = {rv, rv};
                    const f2 tv01 = rvv + ncb01;
                    const f2 tv23 = rvv + ncb23;
                    const f2 qv01 = __builtin_elementwise_fma(tv01, tv01, one2);
                    const f2 qv23 = __builtin_elementwise_fma(tv23, tv23, one2);
                    const float Rv0 = rcp_fast(qv01.x * qv01.y);
                    const float Rv1 = rcp_fast(qv23.x * qv23.y);
                    bv[0] = Rv0 * qv01.y; bv[1] = Rv0 * qv01.x;
                    bv[2] = Rv1 * qv23.y; bv[3] = Rv1 * qv23.x;
                }
#pragma unroll
                for (int mt = 0; mt < 4; ++mt) {
                    aU[mt][jp] = pk_bf16_rhu(aue[mt], auo[mt]);
                    aV[mt][jp] = pk_bf16_rhu(bve[mt], bvo[mt]);
                }
            }

            short8 af[4], bf[4];
#pragma unroll
            for (int mt = 0; mt < 4; ++mt) {
                af[mt] = __builtin_bit_cast(short8,
                    make_int4(aU[mt][0], aU[mt][1], aU[mt][2], aU[mt][3]));
                bf[mt] = __builtin_bit_cast(short8,
                    make_int4(aV[mt][0], aV[mt][1], aV[mt][2], aV[mt][3]));
            }
#pragma unroll
            for (int mt = 0; mt < 4; ++mt)
#pragma unroll
                for (int nt = 0; nt < 4; ++nt)
                    acc[mt * 4 + nt] = __builtin_amdgcn_mfma_f32_16x16x32_bf16(
                        af[mt], bf[nt], acc[mt * 4 + nt], 0, 0, 0);
        }
    }

    // ---- Block-reduce the 4 waves, then atomic-add into global hist ----
    __syncthreads();
    for (int i = tid; i < 4096; i += 256) lds[i] = 0.0f;
    __syncthreads();
#pragma unroll
    for (int mt = 0; mt < 4; ++mt)
#pragma unroll
        for (int nt = 0; nt < 4; ++nt)
#pragma unroll
            for (int i = 0; i < 4; ++i) {
                const int m = mt * 16 + quad * 4 + i;   // C/D: row = quad*4+reg
                const int nn = nt * 16 + l15;           //      col = lane&15
                atomicAdd(&lds[m * 64 + nn], acc[mt * 4 + nt][i]);
            }
    __syncthreads();

    float* __restrict__ hj = hist + (size_t)job * 4096;
    for (int i = tid; i < 4096; i += 256) atomicAdd(&hj[i], lds[i]);
}

// ---------------------------------------------------------------------------
// Kernel 2: per-batch normalization + Hellinger-style distance. 1024 thr/blk.
// ---------------------------------------------------------------------------
__global__ __launch_bounds__(1024) void loss_kernel(
    const float* __restrict__ hist, float* __restrict__ hnorm)
{
    const int b = blockIdx.x;  // 0..7
    __shared__ float red[16];
    const int tid = threadIdx.x;
    const int wv = tid >> 6;
    const float* xh = hist + (size_t)(b * 3) * 4096;        // img 0, batch b
    const float* yh = hist + (size_t)((8 + b) * 3) * 4096;  // img 1, batch b

    float sx = 0.0f, sy = 0.0f;
    for (int i = tid; i < 3 * 4096; i += 1024) { sx += xh[i]; sy += yh[i]; }
    float v = sx;
#pragma unroll
    for (int o = 32; o > 0; o >>= 1) v += __shfl_down(v, o, 64);
    if ((tid & 63) == 0) red[wv] = v;
    __syncthreads();
    float tx = 0.0f;
#pragma unroll
    for (int i = 0; i < 16; ++i) tx += red[i];
    __syncthreads();
    v = sy;
#pragma unroll
    for (int o = 32; o > 0; o >>= 1) v += __shfl_down(v, o, 64);
    if ((tid & 63) == 0) red[wv] = v;
    __syncthreads();
    float ty = 0.0f;
#pragma unroll
    for (int i = 0; i < 16; ++i) ty += red[i];
    __syncthreads();

    const float invx = 1.0f / tx, invy = 1.0f / ty;
    float h = 0.0f;
    for (int i = tid; i < 3 * 4096; i += 1024) {
        const float d = sqrtf(yh[i] * invy) - sqrtf(xh[i] * invx);
        h = fmaf(d, d, h);
    }
#pragma unroll
    for (int o = 32; o > 0; o >>= 1) h += __shfl_down(h, o, 64);
    if ((tid & 63) == 0) red[wv] = h;
    __syncthreads();
    if (tid == 0) {
        float hs = 0.0f;
#pragma unroll
        for (int i = 0; i < 16; ++i) hs += red[i];
        hnorm[b] = sqrtf(0.5f * hs);
    }
}

// ---------------------------------------------------------------------------
// Kernel 3: mean over batch -> out[0]
// ---------------------------------------------------------------------------
__global__ void final_kernel(const float* __restrict__ hnorm, float* __restrict__ out)
{
    if (threadIdx.x == 0) {
        float s = 0.0f;
#pragma unroll
        for (int i = 0; i < 8; ++i) s += hnorm[i];
        out[0] = s * 0.125f;
    }
}

extern "C" void kernel_launch(void* const* d_in, const int* in_sizes, int n_in,
                              void* d_out, int out_size, void* d_ws, size_t ws_size,
                              hipStream_t stream)
{
    const float* x = (const float*)d_in[0];
    const float* y = (const float*)d_in[1];
    float* ws = (float*)d_ws;
    float* hist = ws;                                  // 48*4096 floats (786 KB)
    float* hnorm = ws + (size_t)N_JOBS * 4096;         // 8 floats
    float* outf = (float*)d_out;

    hipMemsetAsync(hist, 0, (size_t)N_JOBS * 4096 * sizeof(float), stream);
    hipLaunchKernelGGL(hist_kernel, dim3(N_JOBS * CHUNKS), dim3(256), 0, stream,
                       x, y, hist);
    hipLaunchKernelGGL(loss_kernel, dim3(8), dim3(1024), 0, stream, hist, hnorm);
    hipLaunchKernelGGL(final_kernel, dim3(1), dim3(64), 0, stream, hnorm, outf);
}